// Round 1
// baseline (287.654 us; speedup 1.0000x reference)
//
#include <hip/hip_runtime.h>
#include <hip/hip_bf16.h>

#define NROWS 32768
#define KCODES 8192
#define DDIM 128
#define BB 16
#define TT 2048
#define ETOT 4194304  // BB*DDIM*TT

typedef __attribute__((ext_vector_type(8))) short bf16x8;
typedef __attribute__((ext_vector_type(4))) float f32x4;

__device__ __forceinline__ void async16(char* lds_uniform, const char* g_perlane) {
    __builtin_amdgcn_global_load_lds(
        (const __attribute__((address_space(1))) unsigned int*)g_perlane,
        (__attribute__((address_space(3))) unsigned int*)lds_uniform,
        16, 0, 0);
}

// ---------------------------------------------------------------------------
// k1: normalize codebook rows, split fp32 -> bf16 hi/lo, store in MFMA
//     fragment-permuted order (per 64-code tile) so the GEMM's LDS stays
//     linear and ds_read_b128 is conflict-free.
// elem offset = tile*8192 + ((ks*4+nf)*64 + q*16 + c)*8 + dr
//   k: tile=k>>6, nf=(k>>4)&3, c=k&15 ; d: ks=d>>5, q=(d>>3)&3, dr=d&7
// ---------------------------------------------------------------------------
__global__ void k_en_prep(const float* __restrict__ cb,
                          __hip_bfloat16* __restrict__ eh,
                          __hip_bfloat16* __restrict__ el) {
    int w = (blockIdx.x * blockDim.x + threadIdx.x) >> 6;  // code id
    int l = threadIdx.x & 63;
    if (w >= KCODES) return;
    const float* row = cb + (long)w * DDIM;
    float v0 = row[l], v1 = row[l + 64];
    float ss = v0 * v0 + v1 * v1;
#pragma unroll
    for (int s = 1; s < 64; s <<= 1) ss += __shfl_xor(ss, s, 64);
    float nrm = fmaxf(sqrtf(ss), 1e-12f);
    float inv = 1.0f / nrm;
    int tile = w >> 6, nf = (w >> 4) & 3, c = w & 15;
#pragma unroll
    for (int e = 0; e < 2; e++) {
        int d = l + e * 64;
        float v = (e ? v1 : v0) * inv;
        __hip_bfloat16 hi = __float2bfloat16(v);
        float hif = __bfloat162float(hi);
        __hip_bfloat16 lo = __float2bfloat16(v - hif);
        int ks = d >> 5, q = (d >> 3) & 3, dr = d & 7;
        long off = (long)tile * 8192 + (((ks * 4 + nf) * 64) + q * 16 + c) * 8 + dr;
        eh[off] = hi;
        el[off] = lo;
    }
}

// ---------------------------------------------------------------------------
// k2: transpose inputs [B,D,T] -> x [N=B*T, D] with bf16 hi/lo split.
// ---------------------------------------------------------------------------
__global__ void k_x_prep(const float* __restrict__ in,
                         __hip_bfloat16* __restrict__ xh,
                         __hip_bfloat16* __restrict__ xl) {
    __shared__ float tb[64][65];
    int bid = blockIdx.x;
    int tt0 = (bid & 31) * 64;
    int dd0 = ((bid >> 5) & 1) * 64;
    int b = bid >> 6;
    const float* base = in + (long)b * DDIM * TT;
    int tl = threadIdx.x & 63;
    int dg = threadIdx.x >> 6;
#pragma unroll
    for (int i = 0; i < 16; i++) {
        int dd = dg + i * 4;
        tb[dd][tl] = base[(long)(dd0 + dd) * TT + tt0 + tl];
    }
    __syncthreads();
    int dl = threadIdx.x & 63;
    int tg = threadIdx.x >> 6;
#pragma unroll
    for (int i = 0; i < 16; i++) {
        int t = tg + i * 4;
        float v = tb[dl][t];
        __hip_bfloat16 hi = __float2bfloat16(v);
        float hif = __bfloat162float(hi);
        __hip_bfloat16 lo = __float2bfloat16(v - hif);
        long n = (long)b * TT + tt0 + t;
        xh[n * DDIM + dd0 + dl] = hi;
        xl[n * DDIM + dd0 + dl] = lo;
    }
}

// ---------------------------------------------------------------------------
// k3: fused similarity GEMM + per-row top-2 (per column-group).
// 256 blocks x 512 threads. Block tile: 128 rows x 64 codes/iter, 128 iters.
// 8 waves = 4 row-groups x 2 col-groups; wave = 32 rows x 32 codes.
// 3-product bf16 split MFMA (hi*hi + lo*hi + hi*lo), fp32 accumulate.
// en staged via global_load_lds into double-buffered LDS (2 x 32KB).
// ---------------------------------------------------------------------------
__launch_bounds__(512, 2)
__global__ void k_main(const __hip_bfloat16* __restrict__ xh,
                       const __hip_bfloat16* __restrict__ xl,
                       const __hip_bfloat16* __restrict__ eh,
                       const __hip_bfloat16* __restrict__ el,
                       int* __restrict__ cand) {
    extern __shared__ char lds[];
    const int tid = threadIdx.x;
    const int l = tid & 63;
    const int w = tid >> 6;          // 0..7
    const int rg = w >> 1, cg = w & 1;
    const int c16 = l & 15, q = l >> 4;
    const long rbase = (long)blockIdx.x * 128;

    // A-fragments in registers (loaded once): rows rg*32 + m*16 + c16,
    // k-slice (l>>4)*8 within each ks*32 block.
    bf16x8 ahi[2][4], alo[2][4];
#pragma unroll
    for (int m = 0; m < 2; m++) {
        long r = rbase + rg * 32 + m * 16 + c16;
        const bf16x8* ph = (const bf16x8*)(xh + r * DDIM);
        const bf16x8* pl = (const bf16x8*)(xl + r * DDIM);
#pragma unroll
        for (int ks = 0; ks < 4; ks++) {
            ahi[m][ks] = ph[ks * 4 + q];
            alo[m][ks] = pl[ks * 4 + q];
        }
    }

    float b1v[8], b2v[8];
    int b1i[8], b2i[8];
#pragma unroll
    for (int i = 0; i < 8; i++) { b1v[i] = -1e30f; b2v[i] = -1e30f; b1i[i] = 0; b2i[i] = 0; }

    const int ou = w * 2048;  // wave-uniform stage offset within a 16KB split-tile
    const int pl16 = ou + l * 16;

    // prologue: stage tile 0 into buf 0
    {
        const char* gh = (const char*)eh;
        const char* gl = (const char*)el;
        async16(lds + ou,                 gh + pl16);
        async16(lds + ou + 1024,          gh + pl16 + 1024);
        async16(lds + 16384 + ou,         gl + pl16);
        async16(lds + 16384 + ou + 1024,  gl + pl16 + 1024);
    }
    __syncthreads();

    for (int t = 0; t < 128; ++t) {
        const int cur = t & 1;
        if (t + 1 < 128) {
            long gb = (long)(t + 1) * 16384;
            char* lb = lds + (cur ^ 1) * 32768;
            const char* gh = (const char*)eh + gb;
            const char* gl = (const char*)el + gb;
            async16(lb + ou,                gh + pl16);
            async16(lb + ou + 1024,         gh + pl16 + 1024);
            async16(lb + 16384 + ou,        gl + pl16);
            async16(lb + 16384 + ou + 1024, gl + pl16 + 1024);
        }

        const char* lb = lds + cur * 32768;
        f32x4 acc[2][2];
#pragma unroll
        for (int m = 0; m < 2; m++)
#pragma unroll
            for (int nf = 0; nf < 2; nf++) acc[m][nf] = (f32x4){0.f, 0.f, 0.f, 0.f};

#pragma unroll
        for (int ks = 0; ks < 4; ks++) {
            bf16x8 bh[2], bl_[2];
#pragma unroll
            for (int nf = 0; nf < 2; nf++) {
                int chunk = (ks * 4 + (cg * 2 + nf)) * 64 + l;
                bh[nf]  = *(const bf16x8*)(lb + chunk * 16);
                bl_[nf] = *(const bf16x8*)(lb + 16384 + chunk * 16);
            }
#pragma unroll
            for (int m = 0; m < 2; m++)
#pragma unroll
                for (int nf = 0; nf < 2; nf++) {
                    acc[m][nf] = __builtin_amdgcn_mfma_f32_16x16x32_bf16(ahi[m][ks], bh[nf],  acc[m][nf], 0, 0, 0);
                    acc[m][nf] = __builtin_amdgcn_mfma_f32_16x16x32_bf16(alo[m][ks], bh[nf],  acc[m][nf], 0, 0, 0);
                    acc[m][nf] = __builtin_amdgcn_mfma_f32_16x16x32_bf16(ahi[m][ks], bl_[nf], acc[m][nf], 0, 0, 0);
                }
        }

        // running top-2 update (codes ascend -> strict > keeps lowest index on tie)
#pragma unroll
        for (int m = 0; m < 2; m++)
#pragma unroll
            for (int nf = 0; nf < 2; nf++) {
                int code = t * 64 + (cg * 2 + nf) * 16 + c16;
#pragma unroll
                for (int j = 0; j < 4; j++) {
                    float v = acc[m][nf][j];
                    int ridx = m * 4 + j;
                    bool gt1 = v > b1v[ridx];
                    bool gt2 = v > b2v[ridx];
                    b2v[ridx] = gt1 ? b1v[ridx] : (gt2 ? v : b2v[ridx]);
                    b2i[ridx] = gt1 ? b1i[ridx] : (gt2 ? code : b2i[ridx]);
                    b1v[ridx] = gt1 ? v : b1v[ridx];
                    b1i[ridx] = gt1 ? code : b1i[ridx];
                }
            }
        __syncthreads();
    }

    // merge top-2 across the 16 lanes of each row group (butterfly)
#pragma unroll
    for (int s = 1; s < 16; s <<= 1) {
#pragma unroll
        for (int i = 0; i < 8; i++) {
            float o1v = __shfl_xor(b1v[i], s, 64);
            int   o1i = __shfl_xor(b1i[i], s, 64);
            float o2v = __shfl_xor(b2v[i], s, 64);
            int   o2i = __shfl_xor(b2i[i], s, 64);
            bool t1 = (o1v > b1v[i]) || (o1v == b1v[i] && o1i < b1i[i]);
            float f1v = t1 ? o1v : b1v[i]; int f1i = t1 ? o1i : b1i[i];
            float c2v = t1 ? b1v[i] : o1v; int c2i = t1 ? b1i[i] : o1i;
            float d2v = t1 ? o2v : b2v[i]; int d2i = t1 ? o2i : b2i[i];
            bool t2 = (c2v > d2v) || (c2v == d2v && c2i < d2i);
            b2v[i] = t2 ? c2v : d2v; b2i[i] = t2 ? c2i : d2i;
            b1v[i] = f1v; b1i[i] = f1i;
        }
    }
    if (c16 == 0) {
#pragma unroll
        for (int m = 0; m < 2; m++)
#pragma unroll
            for (int j = 0; j < 4; j++) {
                long n = rbase + rg * 32 + m * 16 + q * 4 + j;
                int* cp = cand + n * 4 + cg * 2;
                cp[0] = b1i[m * 4 + j];
                cp[1] = b2i[m * 4 + j];
            }
    }
}

// ---------------------------------------------------------------------------
// k4: fp64 exact re-evaluation of the 4 candidates per row; writes final
//     index (int to ws, float to d_out index region). One wave per row.
// ---------------------------------------------------------------------------
__global__ void k_refine(const float* __restrict__ in, const float* __restrict__ cb,
                         const int* __restrict__ cand, int* __restrict__ idx_out,
                         float* __restrict__ idx_f) {
    int n = (blockIdx.x * blockDim.x + threadIdx.x) >> 6;
    int l = threadIdx.x & 63;
    if (n >= NROWS) return;
    int b = n >> 11, t = n & 2047;
    const float* xb = in + (long)b * DDIM * TT + t;
    double x0 = xb[(long)l * TT];
    double x1 = xb[(long)(l + 64) * TT];
    double best = -1e300;
    int bi = 0x7fffffff;
#pragma unroll
    for (int kk = 0; kk < 4; ++kk) {
        int c = cand[n * 4 + kk];
        const float* e = cb + (long)c * DDIM;
        double e0 = e[l], e1 = e[l + 64];
        double dot = x0 * e0 + x1 * e1;
        double nrm = e0 * e0 + e1 * e1;
#pragma unroll
        for (int s = 1; s < 64; s <<= 1) {
            dot += __shfl_xor(dot, s, 64);
            nrm += __shfl_xor(nrm, s, 64);
        }
        double sv = dot / fmax(sqrt(nrm), 1e-12);
        if (sv > best || (sv == best && c < bi)) { best = sv; bi = c; }
    }
    if (l == 0) {
        idx_out[n] = bi;
        idx_f[n] = (float)bi;
    }
}

// ---------------------------------------------------------------------------
// k5: write out = x + (q - x) (fp32 STE emulation) in [B,D,T] order and
//     accumulate per-block fp64 partial sums of (q-x)^2.
// ---------------------------------------------------------------------------
__global__ void k_out_loss(const float* __restrict__ in, const float* __restrict__ cb,
                           const int* __restrict__ idx, float* __restrict__ out,
                           double* __restrict__ part) {
    __shared__ double sd[256];
    double acc = 0.0;
    for (long e = (long)blockIdx.x * blockDim.x + threadIdx.x; e < ETOT;
         e += (long)gridDim.x * blockDim.x) {
        long t = e & 2047;
        long d = (e >> 11) & 127;
        long b = e >> 18;
        float xv = in[e];
        int n = (int)((b << 11) | t);
        float qv = cb[(long)idx[n] * DDIM + d];
        float diff = qv - xv;
        out[e] = xv + diff;
        acc += (double)diff * (double)diff;
    }
    sd[threadIdx.x] = acc;
    __syncthreads();
    for (int s = 128; s > 0; s >>= 1) {
        if (threadIdx.x < s) sd[threadIdx.x] += sd[threadIdx.x + s];
        __syncthreads();
    }
    if (threadIdx.x == 0) part[blockIdx.x] = sd[0];
}

__global__ void k_loss_final(const double* __restrict__ part, int np,
                             float* __restrict__ loss) {
    __shared__ double sd[256];
    double a = 0.0;
    for (int i = threadIdx.x; i < np; i += 256) a += part[i];
    sd[threadIdx.x] = a;
    __syncthreads();
    for (int s = 128; s > 0; s >>= 1) {
        if (threadIdx.x < s) sd[threadIdx.x] += sd[threadIdx.x + s];
        __syncthreads();
    }
    if (threadIdx.x == 0) {
        float m = (float)(sd[0] / (double)ETOT);
        loss[0] = m + 0.02f * m;  // q_latent + commitment * e_latent (both = mse)
    }
}

// ---------------------------------------------------------------------------
extern "C" void kernel_launch(void* const* d_in, const int* in_sizes, int n_in,
                              void* d_out, int out_size, void* d_ws, size_t ws_size,
                              hipStream_t stream) {
    const float* inputs = (const float*)d_in[0];   // [16,128,2048] fp32
    const float* cb     = (const float*)d_in[1];   // [8192,128]    fp32
    float* outf = (float*)d_out;                   // [loss | out(B,D,T) | idx]

    char* ws = (char*)d_ws;
    __hip_bfloat16* xh = (__hip_bfloat16*)ws; ws += (long)NROWS * DDIM * 2;
    __hip_bfloat16* xl = (__hip_bfloat16*)ws; ws += (long)NROWS * DDIM * 2;
    __hip_bfloat16* eh = (__hip_bfloat16*)ws; ws += (long)KCODES * DDIM * 2;
    __hip_bfloat16* el = (__hip_bfloat16*)ws; ws += (long)KCODES * DDIM * 2;
    int* cand   = (int*)ws;    ws += (long)NROWS * 4 * 4;
    int* idx    = (int*)ws;    ws += (long)NROWS * 4;
    double* part = (double*)ws; ws += 2048 * 8;

    k_en_prep<<<dim3(2048), dim3(256), 0, stream>>>(cb, eh, el);
    k_x_prep<<<dim3(1024), dim3(256), 0, stream>>>(inputs, xh, xl);
    k_main<<<dim3(256), dim3(512), 65536, stream>>>(xh, xl, eh, el, cand);
    k_refine<<<dim3(8192), dim3(256), 0, stream>>>(inputs, cb, cand, idx,
                                                   outf + 1 + (long)ETOT);
    k_out_loss<<<dim3(2048), dim3(256), 0, stream>>>(inputs, cb, idx, outf + 1, part);
    k_loss_final<<<dim3(1), dim3(256), 0, stream>>>(part, 2048, outf);
}